// Round 1
// baseline (306.807 us; speedup 1.0000x reference)
//
#include <hip/hip_runtime.h>
#include <hip/hip_bf16.h>
#include <stdint.h>

typedef __bf16 bf16_t;
typedef __bf16 bf16x8 __attribute__((ext_vector_type(8)));
typedef __bf16 bf16x4 __attribute__((ext_vector_type(4)));
typedef float f32x4 __attribute__((ext_vector_type(4)));

#define L_SEQ 4096
#define D_DIM 128
#define NBH   32
#define KT    64

// ============================================================================
// Pre-pass 1: K f32 -> bf16, XOR-swizzled 16B chunks within each 256B row.
// K_ws[bh*L+key][pc] holds logical chunk (pc ^ (key&7)).  This makes the main
// kernel's linear global_load_lds produce a bank-conflict-free LDS layout
// (rule: swizzle source + swizzle read, keep LDS dest linear).
// ============================================================================
__global__ __launch_bounds__(256)
void cvt_k(const float* __restrict__ Kg, bf16_t* __restrict__ Kws) {
    const int n   = blockIdx.x * 256 + threadIdx.x;   // one 16B chunk per thread
    const int key = n >> 4;                            // fused bh*L + key
    const int pc  = n & 15;                            // physical chunk
    const int lc  = pc ^ (key & 7);                    // logical chunk
    const float* s = Kg + (size_t)key * D_DIM + lc * 8;
    f32x4 a = *(const f32x4*)(s);
    f32x4 b = *(const f32x4*)(s + 4);
    bf16x8 h;
    #pragma unroll
    for (int j = 0; j < 4; ++j) { h[j] = (bf16_t)a[j]; h[4 + j] = (bf16_t)b[j]; }
    *(bf16x8*)(Kws + (size_t)key * D_DIM + pc * 8) = h;
}

// ============================================================================
// Pre-pass 2: V f32 -> bf16, transposed into contiguous 64-key tiles:
// V_ws[bh][kb][d][64keys], with 16B-chunk XOR swizzle (chunk ^ (d&7)).
// Each tile is a contiguous 16KB block -> perfectly linear global_load_lds.
// ============================================================================
__global__ __launch_bounds__(256)
void cvt_v(const float* __restrict__ Vg, bf16_t* __restrict__ Vws) {
    const int blk  = blockIdx.x;            // 32 bh x 64 kb
    const int bh   = blk >> 6;
    const int kb   = blk & 63;
    const int t    = threadIdx.x;
    const int d    = t & 127;
    const int half = t >> 7;
    const float* src0 = Vg + (size_t)(bh * L_SEQ + kb * 64) * D_DIM + d;  // coalesced over d
    bf16_t* dstrow = Vws + ((size_t)(bh * 64 + kb) * D_DIM + d) * 64;
    #pragma unroll
    for (int r2 = 0; r2 < 4; ++r2) {
        const int lc = half + 2 * r2;       // logical 8-key chunk 0..7
        bf16x8 h;
        #pragma unroll
        for (int j = 0; j < 8; ++j)
            h[j] = (bf16_t)src0[(size_t)(lc * 8 + j) * D_DIM];
        const int pc = lc ^ (d & 7);
        *(bf16x8*)(&dstrow[pc * 8]) = h;
    }
}

// ============================================================================
// Main kernel: 128 queries/block, 4 waves x 32 queries (2 m-tiles each).
// bf16 K/V from workspace, global_load_lds staging, LDS double-buffered,
// one barrier per tile.  Swapped-operand QK^T (S^T = mfma(K,Q)) so the
// P transpose is 8 packed ds_write_b64 and lsum is lane-local.
// ============================================================================
__device__ __forceinline__ void ld_lds16(const void* g, void* s) {
    __builtin_amdgcn_global_load_lds(
        (const __attribute__((address_space(1))) unsigned int*)g,
        (__attribute__((address_space(3))) unsigned int*)s, 16, 0, 0);
}

#define QT2 128

__global__ __launch_bounds__(256, 2)
void swa_fwd2(const float* __restrict__ Qg,
              const bf16_t* __restrict__ Kws,
              const bf16_t* __restrict__ Vws,
              float* __restrict__ Og) {
    // Swizzled-content tiles, linear addressing (256B / 128B rows).
    __shared__ __align__(16) bf16_t KtS[2][KT * D_DIM];   // 32KB  [key][d]
    __shared__ __align__(16) bf16_t VtS[2][D_DIM * KT];   // 32KB  [d][key]
    __shared__ __align__(16) bf16_t Pst[4][16 * KT];      // 8KB   per-wave P^T strip [q][key]

    const int t    = threadIdx.x;
    const int w    = t >> 6;          // wave 0..3
    const int ln   = t & 15;
    const int quad = (t & 63) >> 4;
    const int l7   = t & 7;           // == ln & 7

    // Balance swizzle: 1024 blocks = 32 qt x 32 bh. CUs see ids at stride 256.
    // qt(g): k=g>>3, r=g&7 -> 8k + (k odd ? 7-r : r).  Per-CU ntile sums:
    // rounds {k0,k1}=26 and {k2,k3}=34 -- constant for every CU.
    const int id = blockIdx.x;
    const int bh = id & 31;
    const int g  = id >> 5;
    const int r_ = g & 7;
    const int k_ = g >> 3;
    const int qt = 8 * k_ + ((k_ & 1) ? (7 - r_) : r_);

    const size_t baseF = (size_t)bh * L_SEQ * D_DIM;
    const float*  Qp = Qg + baseF;
    float*        Op = Og + baseF;
    const bf16_t* Kb = Kws + baseF;                              // [key][d] swizzled
    const bf16_t* Vb = Vws + (size_t)bh * 64 * D_DIM * 64;       // [kb][d][64] swizzled

    const int qbase  = qt * QT2;
    const int blk    = qbase & ~1023;
    const int kstart = (blk - 512) > 0 ? (blk - 512) : 0;
    const int kend   = qbase + QT2;
    const int ntile  = (kend - kstart) / KT;

    // exp2-domain softmax with fixed max (scores bounded ~|8|): fold
    // scale*log2(e) into Q; p = exp2(s - FIX).
    const float SC  = 0.08838834764831845f * 1.4426950408889634f;
    const float FIX = 8.0f;
    const float NEG = -1.0e30f;       // exp2(NEG-FIX) == 0 exactly

    // ---- Q fragments (used as MFMA B-operand: n=ln(query), k=quad*8+j) ----
    bf16x8 qf[2][4];
    #pragma unroll
    for (int mt = 0; mt < 2; ++mt) {
        const float* qrow = Qp + (size_t)(qbase + w * 32 + mt * 16 + ln) * D_DIM + quad * 8;
        #pragma unroll
        for (int ks = 0; ks < 4; ++ks) {
            f32x4 a = *(const f32x4*)(qrow + ks * 32);
            f32x4 b = *(const f32x4*)(qrow + ks * 32 + 4);
            bf16x8 q8;
            #pragma unroll
            for (int j = 0; j < 4; ++j) { q8[j] = (bf16_t)(a[j] * SC); q8[4 + j] = (bf16_t)(b[j] * SC); }
            qf[mt][ks] = q8;
        }
    }

    // O^T accumulators: Oacc[mt][dt] row = d = quad*4+r (+16*dt), col = query = ln
    f32x4 Oacc[2][8];
    #pragma unroll
    for (int mt = 0; mt < 2; ++mt)
        #pragma unroll
        for (int dt = 0; dt < 8; ++dt) Oacc[mt][dt] = f32x4{0.f, 0.f, 0.f, 0.f};
    float lsum[2] = {0.f, 0.f};       // per-lane = per-query denominator partials

    // ---- async staging: 8 x global_load_lds dwordx4 per thread per tile ----
    auto stage = [&](int b, int k0) {
        const char* ksrc = (const char*)Kb + (size_t)k0 * 256;           // contiguous 16KB
        const char* vsrc = (const char*)Vb + (size_t)(k0 >> 6) * 16384;  // contiguous 16KB
        char* kd = (char*)(&KtS[b][0]);
        char* vd = (char*)(&VtS[b][0]);
        #pragma unroll
        for (int i = 0; i < 4; ++i) {
            const int off = (i * 256 + t) * 16;
            ld_lds16(ksrc + off, kd + off);
            ld_lds16(vsrc + off, vd + off);
        }
    };

    stage(0, kstart);
    __syncthreads();                  // drains vmcnt -> buf0 ready

    int buf = 0;
    for (int kt = 0; kt < ntile; ++kt) {
        const int k0 = kstart + kt * KT;
        if (kt + 1 < ntile) stage(buf ^ 1, k0 + KT);   // prefetch: latency hides under compute

        // ---- S^T = K Q^T : A = K-frag (m=key), B = Q-frag (n=query) ----
        f32x4 S[2][4];
        #pragma unroll
        for (int mt = 0; mt < 2; ++mt)
            #pragma unroll
            for (int nt = 0; nt < 4; ++nt) S[mt][nt] = f32x4{0.f, 0.f, 0.f, 0.f};
        #pragma unroll
        for (int ks = 0; ks < 4; ++ks) {
            #pragma unroll
            for (int nt = 0; nt < 4; ++nt) {
                const bf16x8 bk = *(const bf16x8*)(
                    &KtS[buf][(nt * 16 + ln) * D_DIM + (((quad + ks * 4) ^ l7) * 8)]);
                S[0][nt] = __builtin_amdgcn_mfma_f32_16x16x32_bf16(bk, qf[0][ks], S[0][nt], 0, 0, 0);
                S[1][nt] = __builtin_amdgcn_mfma_f32_16x16x32_bf16(bk, qf[1][ks], S[1][nt], 0, 0, 0);
            }
        }

        // ---- softmax (fixed max) + P^T strip (packed b64, swizzled) + frags ----
        bf16x8 pa[2][2];
        #pragma unroll
        for (int mt = 0; mt < 2; ++mt) {
            const int qwm = qbase + w * 32 + mt * 16;
            const int qg  = qwm + ln;                  // this lane's query
            const bool nm = (k0 + KT - 1) > qwm;       // tile crosses causal diagonal?
            #pragma unroll
            for (int nt = 0; nt < 4; ++nt) {
                bf16x4 hp;
                #pragma unroll
                for (int r = 0; r < 4; ++r) {
                    float s = S[mt][nt][r];            // key = k0+nt*16+quad*4+r (lane-local)
                    if (nm) {
                        const int kg = k0 + nt * 16 + quad * 4 + r;
                        if (kg > qg) s = NEG;
                    }
                    const float e = __builtin_amdgcn_exp2f(s - FIX);
                    lsum[mt] += e;
                    hp[r] = (bf16_t)e;
                }
                // P^T[q=ln][key]: 4 consecutive keys -> one b64, chunk ^ (ln&7)
                *(bf16x4*)(&Pst[w][ln * 64 + (((nt * 2 + (quad >> 1)) ^ l7) * 8) + (quad & 1) * 4]) = hp;
            }
            // read back as PV B-operand (n=query=ln, k=key=quad*8+j+32*ks2);
            // same-wave LDS RAW: DS pipe is in-order per wave
            #pragma unroll
            for (int ks2 = 0; ks2 < 2; ++ks2)
                pa[mt][ks2] = *(const bf16x8*)(
                    &Pst[w][ln * 64 + (((quad + ks2 * 4) ^ l7) * 8)]);
        }

        // ---- O^T += V^T P^T : A = V^T-frag (m=d), B = P^T-frag (n=query) ----
        #pragma unroll
        for (int dt = 0; dt < 8; ++dt) {
            #pragma unroll
            for (int ks2 = 0; ks2 < 2; ++ks2) {
                const bf16x8 bv = *(const bf16x8*)(
                    &VtS[buf][(dt * 16 + ln) * 64 + (((quad + ks2 * 4) ^ l7) * 8)]);
                Oacc[0][dt] = __builtin_amdgcn_mfma_f32_16x16x32_bf16(bv, pa[0][ks2], Oacc[0][dt], 0, 0, 0);
                Oacc[1][dt] = __builtin_amdgcn_mfma_f32_16x16x32_bf16(bv, pa[1][ks2], Oacc[1][dt], 0, 0, 0);
            }
        }

        __syncthreads();              // drains prefetch vmcnt; next tile visible
        buf ^= 1;
    }

    // ---- epilogue: lsum is per-query in-lane; reduce across the 4 quads ----
    #pragma unroll
    for (int mt = 0; mt < 2; ++mt) {
        float l = lsum[mt];
        l += __shfl_xor(l, 16, 64);
        l += __shfl_xor(l, 32, 64);
        const float inv = (l > 0.f) ? (1.f / l) : 0.f;
        const int qg = qbase + w * 32 + mt * 16 + ln;
        float* orow = Op + (size_t)qg * D_DIM + quad * 4;
        #pragma unroll
        for (int dt = 0; dt < 8; ++dt) {
            f32x4 o = Oacc[mt][dt];
            #pragma unroll
            for (int j = 0; j < 4; ++j) o[j] *= inv;
            *(f32x4*)(orow + dt * 16) = o;            // d = dt*16 + quad*4 + r
        }
    }
}

// ============================================================================
// Fallback (previous verified kernel) -- used if workspace is too small.
// ============================================================================
#define QT 64
#define LDK 136
#define LDV 72
#define LDP 72

__global__ __launch_bounds__(256, 2)
void swa_fwd(const float* __restrict__ Qg,
             const float* __restrict__ Kg,
             const float* __restrict__ Vg,
             float* __restrict__ Og) {
    __shared__ __align__(16) bf16_t Kt[KT][LDK];
    __shared__ __align__(16) bf16_t Vt[D_DIM][LDV];
    __shared__ __align__(16) bf16_t Pstf[4][16][LDP];

    const int t    = threadIdx.x;
    const int w    = t >> 6;
    const int ln   = t & 15;
    const int quad = (t & 63) >> 4;

    const int id = blockIdx.x;
    const int bh = id & 31;
    const int g  = id >> 5;
    const int q0 = g & 7;
    const int kk = g >> 3;
    const int qt = 16 * (kk >> 1) + ((kk & 1) ? (15 - q0) : q0);

    const size_t base = (size_t)bh * L_SEQ * D_DIM;
    const float* Qp = Qg + base;
    const float* Kp = Kg + base;
    const float* Vp = Vg + base;
    float*       Op = Og + base;

    const int qbase  = qt * QT;
    const int blk    = qbase & ~1023;
    const int kstart = (blk - 512) > 0 ? (blk - 512) : 0;
    const int kend   = qbase + QT;
    const int ntile  = (kend - kstart) / KT;

    const int qw = qbase + w * 16;

    const float SC  = 0.08838834764831845f * 1.4426950408889634f;
    const float FIX = 8.0f;

    bf16x8 qf[4];
    {
        const float* qrow = Qp + (size_t)(qw + ln) * D_DIM + quad * 8;
        #pragma unroll
        for (int ks = 0; ks < 4; ++ks) {
            f32x4 a = *(const f32x4*)(qrow + ks * 32);
            f32x4 b = *(const f32x4*)(qrow + ks * 32 + 4);
            bf16x8 q8;
            #pragma unroll
            for (int j = 0; j < 4; ++j) {
                q8[j]     = (bf16_t)(a[j] * SC);
                q8[4 + j] = (bf16_t)(b[j] * SC);
            }
            qf[ks] = q8;
        }
    }

    f32x4 Oacc[8];
    #pragma unroll
    for (int dt = 0; dt < 8; ++dt) Oacc[dt] = f32x4{0.f, 0.f, 0.f, 0.f};
    float lsum[4] = {0.f, 0.f, 0.f, 0.f};
    const float NEG = -1.0e30f;

    const int kr   = t >> 5;
    const int kc   = t & 31;
    const int vd   = t & 127;
    const int vkcb = t >> 7;

    f32x4 kreg[8];
    float vreg[4][8];

    auto load_tile = [&](int k0) {
        #pragma unroll
        for (int i = 0; i < 8; ++i)
            kreg[i] = *(const f32x4*)(Kp + (size_t)(k0 + kr + 8 * i) * D_DIM + kc * 4);
        #pragma unroll
        for (int r2 = 0; r2 < 4; ++r2) {
            const int kcc = vkcb + 2 * r2;
            #pragma unroll
            for (int j = 0; j < 8; ++j)
                vreg[r2][j] = Vp[(size_t)(k0 + kcc * 8 + j) * D_DIM + vd];
        }
    };
    auto store_tile = [&]() {
        #pragma unroll
        for (int i = 0; i < 8; ++i) {
            bf16x4 h;
            #pragma unroll
            for (int j = 0; j < 4; ++j) h[j] = (bf16_t)kreg[i][j];
            *(bf16x4*)(&Kt[kr + 8 * i][kc * 4]) = h;
        }
        #pragma unroll
        for (int r2 = 0; r2 < 4; ++r2) {
            const int kcc = vkcb + 2 * r2;
            bf16x8 h8;
            #pragma unroll
            for (int j = 0; j < 8; ++j) h8[j] = (bf16_t)vreg[r2][j];
            *(bf16x8*)(&Vt[vd][kcc * 8]) = h8;
        }
    };

    load_tile(kstart);

    for (int kt = 0; kt < ntile; ++kt) {
        const int k0 = kstart + kt * KT;
        __syncthreads();
        store_tile();
        __syncthreads();
        if (kt + 1 < ntile) load_tile(k0 + KT);

        f32x4 S[4];
        #pragma unroll
        for (int nt = 0; nt < 4; ++nt) S[nt] = f32x4{0.f, 0.f, 0.f, 0.f};
        #pragma unroll
        for (int ks = 0; ks < 4; ++ks) {
            #pragma unroll
            for (int nt = 0; nt < 4; ++nt) {
                bf16x8 bk = *(const bf16x8*)(&Kt[nt * 16 + ln][quad * 8 + ks * 32]);
                S[nt] = __builtin_amdgcn_mfma_f32_16x16x32_bf16(qf[ks], bk, S[nt], 0, 0, 0);
            }
        }

        const bool lastTile = (kt == ntile - 1);
        float p[4][4];
        #pragma unroll
        for (int nt = 0; nt < 4; ++nt) {
            #pragma unroll
            for (int r = 0; r < 4; ++r) {
                float s = S[nt][r];
                if (lastTile) {
                    const int kg = k0 + nt * 16 + ln;
                    const int qg = qw + quad * 4 + r;
                    if (kg > qg) s = NEG;
                }
                const float e = __builtin_amdgcn_exp2f(s - FIX);
                p[nt][r] = e;
                lsum[r] += e;
            }
        }

        #pragma unroll
        for (int nt = 0; nt < 4; ++nt)
            #pragma unroll
            for (int r = 0; r < 4; ++r)
                Pstf[w][quad * 4 + r][nt * 16 + ln] = (bf16_t)p[nt][r];

        bf16x8 pa[2];
        #pragma unroll
        for (int ks2 = 0; ks2 < 2; ++ks2)
            pa[ks2] = *(const bf16x8*)(&Pstf[w][ln][quad * 8 + ks2 * 32]);

        #pragma unroll
        for (int dt = 0; dt < 8; ++dt) {
            #pragma unroll
            for (int ks2 = 0; ks2 < 2; ++ks2) {
                bf16x8 bv = *(const bf16x8*)(&Vt[dt * 16 + ln][quad * 8 + ks2 * 32]);
                Oacc[dt] = __builtin_amdgcn_mfma_f32_16x16x32_bf16(pa[ks2], bv, Oacc[dt], 0, 0, 0);
            }
        }
    }

    #pragma unroll
    for (int r = 0; r < 4; ++r) {
        float l = lsum[r];
        #pragma unroll
        for (int msk = 1; msk < 16; msk <<= 1)
            l += __shfl_xor(l, msk, 64);
        const float inv = (l > 0.f) ? (1.f / l) : 0.f;
        const int qg = qw + quad * 4 + r;
        float* orow = Op + (size_t)qg * D_DIM + ln;
        #pragma unroll
        for (int dt = 0; dt < 8; ++dt)
            orow[dt * 16] = Oacc[dt][r] * inv;
    }
}

extern "C" void kernel_launch(void* const* d_in, const int* in_sizes, int n_in,
                              void* d_out, int out_size, void* d_ws, size_t ws_size,
                              hipStream_t stream) {
    const float* q = (const float*)d_in[0];
    const float* k = (const float*)d_in[1];
    const float* v = (const float*)d_in[2];
    float* o = (float*)d_out;

    const size_t kbytes = (size_t)NBH * L_SEQ * D_DIM * sizeof(bf16_t);  // 32MB
    if (d_ws && ws_size >= 2 * kbytes) {
        bf16_t* kws = (bf16_t*)d_ws;
        bf16_t* vws = (bf16_t*)((char*)d_ws + kbytes);
        cvt_k<<<dim3(8192), dim3(256), 0, stream>>>(k, kws);
        cvt_v<<<dim3(2048), dim3(256), 0, stream>>>(v, vws);
        swa_fwd2<<<dim3(1024), dim3(256), 0, stream>>>(q, kws, vws, o);
    } else {
        // workspace too small: previous verified kernel
        swa_fwd<<<dim3(2048), dim3(256), 0, stream>>>(q, k, v, o);
    }
}